// Round 6
// baseline (152.704 us; speedup 1.0000x reference)
//
#include <hip/hip_runtime.h>
#include <math.h>

#define CC 1024
#define SS 16
#define DD 512
#define RR (CC*SS)
#define EPSV 1e-8f

typedef __attribute__((ext_vector_type(8))) short short8;
typedef __attribute__((ext_vector_type(4))) float f32x4;
typedef unsigned short ushort_t;

__device__ __forceinline__ unsigned short f2bf(float f) {
  unsigned u = __float_as_uint(f);
  u += 0x7fffu + ((u >> 16) & 1u);       // RNE
  return (unsigned short)(u >> 16);
}

__device__ __forceinline__ float softplusf(float v) {
  return (v > 20.f) ? v : log1pf(expf(v));
}

// ---------------- Kernel 1: per-class precompute ----------------
// grid = CC blocks x 256 thr. Writes bf16 normalized mean (mn), bf16
// row-normalized x (xn), and sim_pos.
__global__ __launch_bounds__(256) void k_pre(
    const float* __restrict__ x, unsigned* __restrict__ mn,
    float* __restrict__ simpos, ushort_t* __restrict__ xn) {
  __shared__ float xs[SS * DD];
  __shared__ float sums[DD];
  __shared__ float red[4];
  __shared__ float snm;
  __shared__ float rinv[SS];
  const int j = blockIdx.x, tid = threadIdx.x;
  const float4* xj = (const float4*)(x + (size_t)j * SS * DD);
  float4* xs4 = (float4*)xs;
  for (int i = tid; i < SS * DD / 4; i += 256) xs4[i] = xj[i];
  __syncthreads();
  float m2 = 0.f;
  {
    const int d0 = tid * 2;   // 256 threads x 2 cols = 512
    float s0 = 0.f, s1 = 0.f;
#pragma unroll
    for (int i = 0; i < SS; ++i) {
      s0 += xs[i * DD + d0];
      s1 += xs[i * DD + d0 + 1];
    }
    sums[d0] = s0; sums[d0 + 1] = s1;
    float ma = s0 * (1.0f / SS), mb = s1 * (1.0f / SS);
    m2 = fmaf(ma, ma, mb * mb);
  }
#pragma unroll
  for (int off = 32; off > 0; off >>= 1) m2 += __shfl_xor(m2, off, 64);
  const int wid = tid >> 6, lane = tid & 63;
  if (lane == 0) red[wid] = m2;
  __syncthreads();
  if (tid == 0) snm = sqrtf(red[0] + red[1] + red[2] + red[3]);
  __syncthreads();
  const float inm = (1.0f / SS) / snm;
  {
    const int d0 = tid * 2;
    unsigned lo = f2bf(sums[d0] * inm);
    unsigned hi = f2bf(sums[d0 + 1] * inm);
    mn[((size_t)j * DD + d0) >> 1] = lo | (hi << 16);
  }
  for (int i = wid; i < SS; i += 4) {
    float nx2 = 0.f, dxs = 0.f, t2 = 0.f;
    for (int d = lane; d < DD; d += 64) {
      float xv = xs[i * DD + d];
      float sc = sums[d];
      nx2 = fmaf(xv, xv, nx2);
      dxs = fmaf(xv, sc, dxs);
      float tv = sc - xv;
      t2 = fmaf(tv, tv, t2);
    }
#pragma unroll
    for (int off = 32; off > 0; off >>= 1) {
      nx2 += __shfl_xor(nx2, off, 64);
      dxs += __shfl_xor(dxs, off, 64);
      t2  += __shfl_xor(t2,  off, 64);
    }
    if (lane == 0) {
      float nxv = sqrtf(nx2);
      float tn  = sqrtf(t2);
      float num = (dxs - nx2) * (1.0f / (SS - 1));
      float den = fmaxf(nxv * tn * (1.0f / (SS - 1)), EPSV);
      rinv[i] = 1.0f / nxv;
      simpos[j * SS + i] = num / den;
    }
  }
  __syncthreads();
  {
    uint2* dst = (uint2*)(xn + (size_t)j * SS * DD);
    for (int idx = tid; idx < SS * DD / 4; idx += 256) {
      const int e = idx * 4;                 // 4 elems, same row (DD=512)
      const float ri = rinv[e >> 9];
      unsigned a = f2bf(xs[e] * ri),     b2 = f2bf(xs[e + 1] * ri);
      unsigned c = f2bf(xs[e + 2] * ri), d2 = f2bf(xs[e + 3] * ri);
      dst[idx] = make_uint2(a | (b2 << 16), c | (d2 << 16));
    }
  }
}

// ---------------- Kernel 2: LDS-free MFMA GEMM + fused exp-sum ----------------
// grid = 512 blocks (cb-major: bid = cb*128 + rb) x 256 thr, ZERO LDS.
// Wave = 32 rows (2 x 16-row tiles, af resident = 128 VGPR); block = 128
// rows; col-split x4 (256 cols each). B-fragments are loaded directly from
// L2-resident mn (1 MB): lane (cL,quad) reads mn[(c0+cL)*512 + kc*32+quad*8]
// — contiguous 16 B, one addr reg + imm offsets. No __syncthreads anywhere.
__global__ __launch_bounds__(256, 2) void k_gemm(
    const ushort_t* __restrict__ xn, const ushort_t* __restrict__ mn,
    const float* __restrict__ simpos, const float* __restrict__ wptr,
    const float* __restrict__ bptr, float* __restrict__ ps) {
  const int tid = threadIdx.x;
  const int wid = tid >> 6, lane = tid & 63;
  const int cL = lane & 15, quad = lane >> 4;
  const int bid = blockIdx.x;
  const int rb = bid & 127, cb = bid >> 7;   // cb-major => col-splits share XCD
  const int r0 = rb * 128 + wid * 32;
  const int cbase = cb * 256;
  const float wp = softplusf(wptr[0]), bv = bptr[0];

  short8 af[2][16];
  int jw[2];
  float sp[2][4], sacc[2][4];
#pragma unroll
  for (int rt = 0; rt < 2; ++rt) {
    const int row = r0 + rt * 16 + cL;
    const short8* src = (const short8*)(xn + (size_t)row * DD);
#pragma unroll
    for (int kc = 0; kc < 16; ++kc) af[rt][kc] = src[kc * 4 + quad];
    jw[rt] = (r0 + rt * 16) >> 4;
#pragma unroll
    for (int r = 0; r < 4; ++r) {
      sp[rt][r] = simpos[r0 + rt * 16 + quad * 4 + r];
      sacc[rt][r] = 0.f;
    }
  }

  for (int t = 0; t < 16; ++t) {
    const int c0 = cbase + t * 16;
    const ushort_t* bsrc = mn + (size_t)(c0 + cL) * DD + quad * 8;
    f32x4 a0 = {0.f, 0.f, 0.f, 0.f}, a1 = {0.f, 0.f, 0.f, 0.f};
#pragma unroll
    for (int kc = 0; kc < 16; ++kc) {
      const short8 bfr = *(const short8*)(bsrc + kc * 32);
      a0 = __builtin_amdgcn_mfma_f32_16x16x32_bf16(af[0][kc], bfr, a0, 0, 0, 0);
      a1 = __builtin_amdgcn_mfma_f32_16x16x32_bf16(af[1][kc], bfr, a1, 0, 0, 0);
    }
    const bool d0 = (c0 + cL == jw[0]), d1 = (c0 + cL == jw[1]);
#pragma unroll
    for (int r = 0; r < 4; ++r) {
      const float s0 = d0 ? sp[0][r] : a0[r];
      const float s1 = d1 ? sp[1][r] : a1[r];
      sacc[0][r] += __expf(fmaf(wp, s0, bv));
      sacc[1][r] += __expf(fmaf(wp, s1, bv));
    }
  }

#pragma unroll
  for (int rt = 0; rt < 2; ++rt)
#pragma unroll
    for (int r = 0; r < 4; ++r) {
      float v = sacc[rt][r];
#pragma unroll
      for (int off = 1; off < 16; off <<= 1) v += __shfl_xor(v, off, 64);
      if (cL == 0)
        ps[(size_t)(r0 + rt * 16 + quad * 4 + r) * 4 + cb] = v;
    }
}

// ---------------- Kernel 3: per-row loss + block reduce ----------------
__global__ __launch_bounds__(256) void k_combine(
    const float* __restrict__ ps, const float* __restrict__ simpos,
    const float* __restrict__ wptr, const float* __restrict__ bptr,
    float* __restrict__ p2) {
  __shared__ float red[4];
  const int tid = threadIdx.x;
  const int row = blockIdx.x * 256 + tid;
  const float wp = softplusf(wptr[0]), bv = bptr[0];
  const float4 s4 = *(const float4*)(ps + (size_t)row * 4);
  const float s = (s4.x + s4.y) + (s4.z + s4.w);
  float v = logf(s) - fmaf(wp, simpos[row], bv);
#pragma unroll
  for (int off = 32; off > 0; off >>= 1) v += __shfl_xor(v, off, 64);
  if ((tid & 63) == 0) red[tid >> 6] = v;
  __syncthreads();
  if (tid == 0) p2[blockIdx.x] = red[0] + red[1] + red[2] + red[3];
}

__global__ __launch_bounds__(64) void k_fin(const float* __restrict__ p2,
                                            float* __restrict__ out) {
  const int tid = threadIdx.x;
  float v = p2[tid];
#pragma unroll
  for (int off = 32; off > 0; off >>= 1) v += __shfl_xor(v, off, 64);
  if (tid == 0) out[0] = v * (1.0f / RR);
}

extern "C" void kernel_launch(void* const* d_in, const int* in_sizes, int n_in,
                              void* d_out, int out_size, void* d_ws, size_t ws_size,
                              hipStream_t stream) {
  const float* x = (const float*)d_in[0];
  const float* w = (const float*)d_in[1];
  const float* b = (const float*)d_in[2];
  float* out = (float*)d_out;

  char* p = (char*)d_ws;
  ushort_t* xn  = (ushort_t*)p;  p += (size_t)RR * DD * 2;   // 16 MB
  ushort_t* mn  = (ushort_t*)p;  p += (size_t)CC * DD * 2;   // 1 MB
  float* simpos = (float*)p;     p += (size_t)RR * 4;        // 64 KB
  float* ps     = (float*)p;     p += (size_t)RR * 4 * 4;    // 256 KB
  float* p2     = (float*)p;

  k_pre<<<CC, 256, 0, stream>>>(x, (unsigned*)mn, simpos, xn);
  k_gemm<<<512, 256, 0, stream>>>(xn, mn, simpos, w, b, ps);
  k_combine<<<RR / 256, 256, 0, stream>>>(ps, simpos, w, b, p2);
  k_fin<<<1, 64, 0, stream>>>(p2, out);
}